// Round 6
// baseline (414.395 us; speedup 1.0000x reference)
//
#include <hip/hip_runtime.h>

// ---------------- constants ----------------
#define BATCH 4
#define NPIL 12000
#define NPTS 32
#define NCH 9
#define NXg 432
#define NYg 496
#define OHh 248
#define OWw 216
#define HWp (OHh*OWw)          // 53568
#define CAN_STRIDE ((size_t)NYg*NXg*64)      // ushort elems (bf16 canvas)
#define X1_STRIDE  ((size_t)OHh*OWw*64)      // ushort elems (bf16 x1)
#define MASKW 8192                            // mask words per batch (padded)

typedef __bf16 bf16x8 __attribute__((ext_vector_type(8)));
typedef float  f32x4  __attribute__((ext_vector_type(4)));

__device__ __forceinline__ bf16x8 as_bf16x8(uint4 u) {
    union { uint4 u; bf16x8 b; } c; c.u = u; return c.b;
}

__device__ __forceinline__ float b2f(unsigned int u) {
    union { unsigned int i; float f; } x; x.i = (u & 0xffffu) << 16; return x.f;
}
__device__ __forceinline__ unsigned short f2b(float f) {
    union { float f; unsigned int i; } x; x.f = f;
    unsigned int r = x.i + 0x7fffu + ((x.i >> 16) & 1u);   // RNE
    return (unsigned short)(r >> 16);
}
__device__ __forceinline__ float ldin(const void* p, int i, int isbf) {
    return isbf ? b2f(((const unsigned short*)p)[i]) : ((const float*)p)[i];
}

__global__ void sentinel_kernel(float* out, float val) {
    if (threadIdx.x == 0) out[0] = val;
}

// ---------------- per-tensor dtype detector (robustness; all fp32 in practice) ----------------
__device__ __forceinline__ int plaus16(unsigned short h) {
    if ((h & 0x7fffu) == 0) return 1;
    unsigned e = (h >> 7) & 0xffu;
    return (e >= 106 && e <= 132) ? 1 : 0;
}

__global__ __launch_bounds__(1024) void detect_all(
    const void* q0,  const void* q1,  const void* q2,  const void* q3,
    const void* q4,  const void* q5,  const void* q6,  const void* q7,
    const void* q8,  const void* q9,  const void* q10, const void* q11,
    const void* q12, const void* q13, const void* q14, const void* q15,
    const void* q16, const void* q17, const void* q18, const void* q19,
    const void* q20, const void* q21, int* __restrict__ flags)
{
    __shared__ int votes[22];
    const void* ptrs[22] = {q0,q1,q2,q3,q4,q5,q6,q7,q8,q9,q10,q11,
                            q12,q13,q14,q15,q16,q17,q18,q19,q20,q21};
    const int Ks[22]   = {64,64,32,32,32,32,64,32,32,32,32,64,64,64,64,64,64,3,64,7,64,2};
    const int didx[22] = {0,3,4,5,6,7,8,9,10,11,12,13,14,15,16,17,18,19,20,21,22,23};
    const int tid = threadIdx.x;
    if (tid < 22) votes[tid] = 0;
    __syncthreads();
    int off = 0;
    #pragma unroll 1
    for (int t = 0; t < 22; ++t) {
        const int K = Ks[t];
        if (tid >= off && tid < off + K) {
            unsigned w = ((const unsigned*)ptrs[t])[tid - off];
            if (plaus16((unsigned short)w) && plaus16((unsigned short)(w >> 16)))
                atomicAdd(&votes[t], 1);
        }
        off += K;
    }
    __syncthreads();
    if (tid < 22) {
        int isbf;
        if (tid == 17 || tid == 19 || tid == 21) {
            int pv = votes[17] + votes[19] + votes[21];
            isbf = (pv * 4 >= 3 * 12);
        } else {
            isbf = (votes[tid] * 4 >= 3 * Ks[tid]);
        }
        flags[didx[tid]] = isbf;
    }
}

// ---------------- weight prep ----------------
__global__ __launch_bounds__(256) void prep_weights(
    const void* __restrict__ w1, const void* __restrict__ w2,
    const void* __restrict__ cls_w, const void* __restrict__ reg_w, const void* __restrict__ dir_w,
    unsigned short* __restrict__ wt1, unsigned short* __restrict__ wt2,
    unsigned short* __restrict__ whh, unsigned short* __restrict__ whl,
    const int* __restrict__ flags)
{
    const int f1 = flags[8], f2 = flags[13];
    int i = blockIdx.x * 256 + threadIdx.x;
    if (i < 64*64*9) {
        int kx = i % 3; int t = i / 3; int ky = t % 3; t /= 3; int ic = t % 64; int oc = t / 64;
        wt1[((size_t)(ky*3 + kx)*64 + oc)*64 + ic] = f2b(ldin(w1, i, f1));
    }
    if (i < 128*64*9) {
        int kx = i % 3; int t = i / 3; int ky = t % 3; t /= 3; int ic = t % 64; int oc = t / 64;
        wt2[((size_t)(ky*3 + kx)*128 + oc)*64 + ic] = f2b(ldin(w2, i, f2));
    }
    if (i < 32*128) {
        int ic = i & 127, o = i >> 7;
        float wv = 0.f;
        if (o < 6)       wv = ldin(cls_w, o*128 + ic, flags[18]);
        else if (o < 20) wv = ldin(reg_w, (o-6)*128 + ic, flags[20]);
        else if (o < 24) wv = ldin(dir_w, (o-20)*128 + ic, flags[22]);
        unsigned short hi = f2b(wv);
        whh[i] = hi;
        whl[i] = f2b(wv - b2f(hi));
    }
}

// ---------------- PFN + scatter, canvas NHWC bf16 [NY,NX,64] + occupancy mask ----------------
__global__ __launch_bounds__(256) void pfn_scatter(
    const void* __restrict__ pillars, const int* __restrict__ coords,
    const void* __restrict__ pfn_w,
    const void* __restrict__ g, const void* __restrict__ bb,
    const void* __restrict__ m, const void* __restrict__ v,
    const int* __restrict__ flags, int b0,
    unsigned int* __restrict__ mask,
    unsigned short* __restrict__ canvas)
{
    __shared__ float lds[4][NPTS*NCH];
    const int wslot = threadIdx.x >> 6;
    const int lane  = threadIdx.x & 63;
    const int p = blockIdx.x * 4 + wslot;
    const int b = b0 + blockIdx.y;
    canvas += (size_t)blockIdx.y * CAN_STRIDE;
    mask   += (size_t)blockIdx.y * MASKW;
    const size_t pg = (size_t)b * NPIL + p;

    if (flags[0]) {
        const unsigned short* src = (const unsigned short*)pillars + pg * (NPTS*NCH);
        for (int idx = lane; idx < NPTS*NCH; idx += 64) lds[wslot][idx] = b2f(src[idx]);
    } else {
        const float4* src = (const float4*)((const float*)pillars + pg * (NPTS*NCH));
        for (int idx = lane; idx < (NPTS*NCH)/4; idx += 64)
            *(float4*)&lds[wslot][idx*4] = src[idx];
    }
    float w[NCH];
    const int fW = flags[3];
    #pragma unroll
    for (int c = 0; c < NCH; ++c) w[c] = ldin(pfn_w, lane*NCH + c, fW);
    float s = ldin(g, lane, flags[4]) / sqrtf(ldin(v, lane, flags[7]) + 1e-5f);
    float t = ldin(bb, lane, flags[5]) - ldin(m, lane, flags[6]) * s;
    __syncthreads();

    float mx = 0.0f;
    #pragma unroll 4
    for (int n = 0; n < NPTS; ++n) {
        const float* r = &lds[wslot][n*NCH];
        float acc = r[0] * w[0];
        #pragma unroll
        for (int c = 1; c < NCH; ++c) acc = fmaf(r[c], w[c], acc);
        mx = fmaxf(mx, fmaxf(fmaf(acc, s, t), 0.0f));
    }
    const int cx = coords[pg*2], cy = coords[pg*2 + 1];
    if (cx + cy != 0 && cx >= 0 && cx < NXg && cy >= 0 && cy < NYg) {
        const int cell = cy*NXg + cx;
        canvas[(size_t)cell*64 + lane] = f2b(mx);
        if (lane == 0) atomicOr(&mask[cell >> 5], 1u << (cell & 31));
    }
}

// B-fragment loader for conv1 (direct from L2-resident wt1)
#define LDB1(buf, tap, ks) { \
    _Pragma("unroll") \
    for (int j_ = 0; j_ < 4; ++j_) \
        buf[j_] = *(const uint4*)&wt[((size_t)((tap)*64 + j_*16 + lr))*64 + (ks)*32 + lg*8]; \
}

// ---------------- conv1 (MFMA): canvas bf16 -> x1 bf16 [248,216,64], stride 2 ----------------
// 256 thr, 4 waves x 2 oy m-tiles (8-oy tile). B direct from global wt1 with 2-phase register
// prefetch. Mask-gated canvas reads. LDS 33,792 B. (256,3): 170-reg budget -> no spill;
// residency still up to 4 blk/CU if compiler stays <=128 total regs.
__global__ __launch_bounds__(256, 3) void conv1_mfma(
    const unsigned short* __restrict__ canvas,
    const unsigned int* __restrict__ mask,
    const unsigned short* __restrict__ wt,     // bf16 [9][64 oc][64 ic]
    const void* __restrict__ g, const void* __restrict__ bb,
    const void* __restrict__ m, const void* __restrict__ v,
    const int* __restrict__ flags,
    unsigned short* __restrict__ x1)
{
    __shared__ __align__(16) uint4 lin[8*33*8];    // 33,792 B
    const int tid = threadIdx.x;
    const int w = tid >> 6, l = tid & 63;
    const int lr = l & 15, lg = l >> 4;
    const int px0 = blockIdx.x * 16, oy0 = blockIdx.y * 8;
    canvas += (size_t)blockIdx.z * CAN_STRIDE;
    mask   += (size_t)blockIdx.z * MASKW;
    x1     += (size_t)blockIdx.z * X1_STRIDE;

    f32x4 acc[2][4];
    #pragma unroll
    for (int t = 0; t < 2; ++t)
        #pragma unroll
        for (int n = 0; n < 4; ++n) acc[t][n] = (f32x4){0.f,0.f,0.f,0.f};

    uint4 wbA[4], wbB[4];
    LDB1(wbA, 0, 0);

    #pragma unroll 1
    for (int ky = 0; ky < 3; ++ky) {
        __syncthreads();                       // drain readers of lin
        for (int q = tid; q < 8*33*8; q += 256) {
            int sl = q & 7, t2 = q >> 3, c = t2 % 33, r = t2 / 33;
            int iy = 2*oy0 + ky - 1 + 2*r, gx = 2*px0 - 1 + c;
            uint4 d = make_uint4(0u,0u,0u,0u);
            if ((unsigned)iy < (unsigned)NYg && (unsigned)gx < (unsigned)NXg) {
                const int cell = iy*NXg + gx;
                if ((mask[cell >> 5] >> (cell & 31)) & 1u)
                    d = *(const uint4*)&canvas[(size_t)cell*64 + sl*8];
            }
            lin[(r*33 + c)*8 + (sl ^ ((c >> 1) & 7))] = d;
        }
        __syncthreads();
        #pragma unroll 1
        for (int kx = 0; kx < 3; ++kx) {
            const int tap = ky*3 + kx;
            const int c = 2*lr + kx;
            const int key = (c >> 1) & 7;
            // phase 0: ks=0 with wbA; prefetch ks=1 -> wbB
            LDB1(wbB, tap, 1);
            #pragma unroll
            for (int t = 0; t < 2; ++t) {
                const int base = ((2*w + t)*33 + c)*8;
                bf16x8 a0 = as_bf16x8(lin[base + (lg ^ key)]);
                #pragma unroll
                for (int n = 0; n < 4; ++n)
                    acc[t][n] = __builtin_amdgcn_mfma_f32_16x16x32_bf16(a0, as_bf16x8(wbA[n]), acc[t][n], 0, 0, 0);
            }
            // phase 1: ks=1 with wbB; prefetch next tap ks=0 -> wbA
            if (tap < 8) LDB1(wbA, tap + 1, 0);
            #pragma unroll
            for (int t = 0; t < 2; ++t) {
                const int base = ((2*w + t)*33 + c)*8;
                bf16x8 a1 = as_bf16x8(lin[base + ((4 + lg) ^ key)]);
                #pragma unroll
                for (int n = 0; n < 4; ++n)
                    acc[t][n] = __builtin_amdgcn_mfma_f32_16x16x32_bf16(a1, as_bf16x8(wbB[n]), acc[t][n], 0, 0, 0);
            }
        }
    }
    float s[4], tt[4];
    #pragma unroll
    for (int n = 0; n < 4; ++n) {
        const int oc = n*16 + lr;
        s[n]  = ldin(g, oc, flags[9]) / sqrtf(ldin(v, oc, flags[12]) + 1e-5f);
        tt[n] = ldin(bb, oc, flags[10]) - ldin(m, oc, flags[11]) * s[n];
    }
    // D: col = lr = oc, row = lg*4+r = px
    #pragma unroll
    for (int t = 0; t < 2; ++t) {
        const int oy = oy0 + 2*w + t;
        if (oy >= OHh) continue;
        #pragma unroll
        for (int r = 0; r < 4; ++r) {
            const int px = px0 + lg*4 + r;
            if (px >= OWw) continue;
            unsigned short* orow = &x1[((size_t)oy*OWw + px)*64 + lr];
            #pragma unroll
            for (int n = 0; n < 4; ++n)
                orow[n*16] = f2b(fmaxf(fmaf(acc[t][n][r], s[n], tt[n]), 0.f));
        }
    }
}

// ---------------- conv2 (MFMA) + fused heads ----------------
// 256 thr, 4 waves x 2 oy m-tiles (8-oy tile) x 8 n-tiles (128 oc). lin 10x18x8 (23 KB)
// staged once; lw single-buffered 16 KB staged per tap (block-shared weights, 2 barriers/tap).
// LDS 39,424 B. (256,3): 170-reg budget (64 acc AGPR + ~100 VGPR fits, NO spill — r5's
// (256,4)=128 budget spilled 220 MB to scratch) -> 3 blk/CU = 12 waves/CU.
__global__ __launch_bounds__(256, 3) void conv2_mfma(
    const unsigned short* __restrict__ x1,
    const unsigned short* __restrict__ wt,     // bf16 [9][128 oc][64 ic]
    const unsigned short* __restrict__ whh,    // bf16 [32 o][128 ic] head W hi
    const unsigned short* __restrict__ whl,    // bf16 [32 o][128 ic] head W lo
    const void* __restrict__ g, const void* __restrict__ bb,
    const void* __restrict__ m, const void* __restrict__ v,
    const void* __restrict__ cls_b, const void* __restrict__ reg_b, const void* __restrict__ dir_b,
    const int* __restrict__ flags, int b0,
    float* __restrict__ out)
{
    __shared__ __align__(16) char smem[39424];     // lin 23,040 | lw 16,384 ; P overlays 32,768
    uint4* lin = (uint4*)smem;                     // 10*18*8 = 1440 uint4
    uint4* lw  = (uint4*)(smem + 23040);           // 128*8 = 1024 uint4
    unsigned short* P = (unsigned short*)smem;     // 128 px x 128 ch

    const int tid = threadIdx.x;
    const int w = tid >> 6, l = tid & 63;
    const int lr = l & 15, lg = l >> 4;
    const int px0 = blockIdx.x * 16, oy0 = blockIdx.y * 8;
    const int b = b0 + blockIdx.z;
    x1 += (size_t)blockIdx.z * X1_STRIDE;

    for (int q = tid; q < 10*18*8; q += 256) {
        int sl = q & 7, t2 = q >> 3, c = t2 % 18, r = t2 / 18;
        int iy = oy0 - 1 + r, gx = px0 - 1 + c;
        uint4 d = make_uint4(0u,0u,0u,0u);
        if ((unsigned)iy < (unsigned)OHh && (unsigned)gx < (unsigned)OWw)
            d = *(const uint4*)&x1[((size_t)(iy*OWw + gx))*64 + sl*8];
        lin[(r*18 + c)*8 + (sl ^ (c & 7))] = d;
    }

    f32x4 acc[2][8];
    #pragma unroll
    for (int t = 0; t < 2; ++t)
        #pragma unroll
        for (int n = 0; n < 8; ++n) acc[t][n] = (f32x4){0.f,0.f,0.f,0.f};

    #pragma unroll 1
    for (int tap = 0; tap < 9; ++tap) {
        const int ky = tap / 3, kx = tap - 3*ky;
        __syncthreads();                       // lw free of prev readers (covers lin stage at tap 0)
        #pragma unroll
        for (int i = 0; i < 4; ++i) {
            const int q = tid + i*256, sl = q & 7, oc = q >> 3;
            lw[oc*8 + (sl ^ (oc & 7))] = *(const uint4*)&wt[((size_t)(tap*128 + oc))*64 + sl*8];
        }
        __syncthreads();
        const int c = lr + kx;
        const int key = c & 7;
        bf16x8 a0[2], a1[2];
        #pragma unroll
        for (int t = 0; t < 2; ++t) {
            const int base = ((2*w + t + ky)*18 + c)*8;
            a0[t] = as_bf16x8(lin[base + (lg ^ key)]);
            a1[t] = as_bf16x8(lin[base + ((4 + lg) ^ key)]);
        }
        #pragma unroll
        for (int n = 0; n < 8; ++n) {
            const int oc = n*16 + lr;
            const bf16x8 b0 = as_bf16x8(lw[oc*8 + (lg ^ (oc & 7))]);
            const bf16x8 b1 = as_bf16x8(lw[oc*8 + ((4 + lg) ^ (oc & 7))]);
            #pragma unroll
            for (int t = 0; t < 2; ++t) {
                acc[t][n] = __builtin_amdgcn_mfma_f32_16x16x32_bf16(a0[t], b0, acc[t][n], 0, 0, 0);
                acc[t][n] = __builtin_amdgcn_mfma_f32_16x16x32_bf16(a1[t], b1, acc[t][n], 0, 0, 0);
            }
        }
    }

    float s[8], tt[8];
    #pragma unroll
    for (int n = 0; n < 8; ++n) {
        const int oc = n*16 + lr;
        s[n]  = ldin(g, oc, flags[14]) / sqrtf(ldin(v, oc, flags[17]) + 1e-5f);
        tt[n] = ldin(bb, oc, flags[15]) - ldin(m, oc, flags[16]) * s[n];
    }

    // ---- fused heads ----
    float bias0, bias1;
    {
        int o = lr;
        bias0 = (o < 6) ? ldin(cls_b, o, flags[19]) : ldin(reg_b, o - 6, flags[21]);
        o = 16 + lr;
        bias1 = (o < 20) ? ldin(reg_b, o - 6, flags[21])
              : (o < 24) ? ldin(dir_b, o - 20, flags[23]) : 0.f;
    }

    __syncthreads();            // all waves done reading lin/lw before P overlay
    // write hi (P rows = oy_loc*16 + px_x); acc becomes lo residual
    #pragma unroll
    for (int t = 0; t < 2; ++t) {
        const int pb = ((2*w + t)*16 + lg*4) * 128;
        #pragma unroll
        for (int n = 0; n < 8; ++n) {
            const int kk = 2*n + (lr >> 3), wi = lr & 7;
            #pragma unroll
            for (int r = 0; r < 4; ++r) {
                float val = fmaxf(fmaf(acc[t][n][r], s[n], tt[n]), 0.f);
                unsigned short h = f2b(val);
                P[pb + r*128 + ((kk ^ (lg*4 + r)) << 3) + wi] = h;
                acc[t][n][r] = val - b2f(h);
            }
        }
    }
    __syncthreads();

    f32x4 hacc[2][2];
    #pragma unroll
    for (int t = 0; t < 2; ++t) {
        hacc[t][0] = (f32x4){bias0, bias0, bias0, bias0};
        hacc[t][1] = (f32x4){bias1, bias1, bias1, bias1};
    }
    // pass 1: hi*Whi + hi*Wlo (head weights loaded per-use, L2-hot)
    #pragma unroll
    for (int t = 0; t < 2; ++t) {
        const int mt = 2*w + t;
        bf16x8 pa[4];
        #pragma unroll
        for (int ks = 0; ks < 4; ++ks)
            pa[ks] = as_bf16x8(((const uint4*)P)[(mt*16 + lr)*16 + ((ks*4 + lg) ^ lr)]);
        #pragma unroll
        for (int n = 0; n < 2; ++n)
            #pragma unroll
            for (int ks = 0; ks < 4; ++ks) {
                const int ei = (n*16 + lr)*128 + ks*32 + lg*8;
                hacc[t][n] = __builtin_amdgcn_mfma_f32_16x16x32_bf16(pa[ks], as_bf16x8(*(const uint4*)&whh[ei]), hacc[t][n], 0, 0, 0);
                hacc[t][n] = __builtin_amdgcn_mfma_f32_16x16x32_bf16(pa[ks], as_bf16x8(*(const uint4*)&whl[ei]), hacc[t][n], 0, 0, 0);
            }
    }
    __syncthreads();
    // write lo
    #pragma unroll
    for (int t = 0; t < 2; ++t) {
        const int pb = ((2*w + t)*16 + lg*4) * 128;
        #pragma unroll
        for (int n = 0; n < 8; ++n) {
            const int kk = 2*n + (lr >> 3), wi = lr & 7;
            #pragma unroll
            for (int r = 0; r < 4; ++r)
                P[pb + r*128 + ((kk ^ (lg*4 + r)) << 3) + wi] = f2b(acc[t][n][r]);
        }
    }
    __syncthreads();
    // pass 2: lo*Whi
    #pragma unroll
    for (int t = 0; t < 2; ++t) {
        const int mt = 2*w + t;
        bf16x8 pa[4];
        #pragma unroll
        for (int ks = 0; ks < 4; ++ks)
            pa[ks] = as_bf16x8(((const uint4*)P)[(mt*16 + lr)*16 + ((ks*4 + lg) ^ lr)]);
        #pragma unroll
        for (int n = 0; n < 2; ++n)
            #pragma unroll
            for (int ks = 0; ks < 4; ++ks) {
                const int ei = (n*16 + lr)*128 + ks*32 + lg*8;
                hacc[t][n] = __builtin_amdgcn_mfma_f32_16x16x32_bf16(pa[ks], as_bf16x8(*(const uint4*)&whh[ei]), hacc[t][n], 0, 0, 0);
            }
    }

    const size_t regbase = (size_t)BATCH*6*HWp;
    const size_t dirbase = regbase + (size_t)BATCH*14*HWp;
    const int pxw = px0 + lg*4;
    #pragma unroll
    for (int n = 0; n < 2; ++n) {
        const int o = n*16 + lr;
        float* plane;
        bool valid = (pxw < OWw);
        if (o < 6)       plane = out + ((size_t)b*6 + o)*HWp;
        else if (o < 20) plane = out + regbase + ((size_t)b*14 + (o - 6))*HWp;
        else if (o < 24) plane = out + dirbase + ((size_t)b*4 + (o - 20))*HWp;
        else valid = false;
        if (!valid) continue;
        #pragma unroll
        for (int t = 0; t < 2; ++t) {
            const int oy = oy0 + 2*w + t;
            if (oy < OHh)
                *(float4*)&plane[(size_t)oy*OWw + pxw] = *(float4*)&hacc[t][n];
        }
    }
}

extern "C" void kernel_launch(void* const* d_in, const int* in_sizes, int n_in,
                              void* d_out, int out_size, void* d_ws, size_t ws_size,
                              hipStream_t stream) {
    static const int EXPECT[24] = {13824000,96000,48000,576,64,64,64,64,36864,
                                   64,64,64,64,73728,128,128,128,128,768,6,1792,14,512,4};
    const void* din[24];
    {
        bool used[24] = {false};
        int perm[24];
        bool ok = (n_in >= 24);
        if (ok) {
            for (int j = 0; j < 24 && ok; ++j) {
                perm[j] = -1;
                for (int i = 0; i < 24; ++i)
                    if (!used[i] && in_sizes[i] == EXPECT[j]) { perm[j] = i; used[i] = true; break; }
                if (perm[j] < 0) ok = false;
            }
        }
        for (int j = 0; j < 24; ++j) din[j] = d_in[ok ? perm[j] : j];
        if (!ok) {
            sentinel_kernel<<<1, 64, 0, stream>>>((float*)d_out, 13000.0f + n_in);
            return;
        }
    }
    const int* coords = (const int*)din[1];
    float* out = (float*)d_out;

    // layout: flags 256 | wt1 73,728 | wt2 147,456 | whh 8,192 | whl 8,192 |
    //         mask (nb x 32,768) | x1 bf16 (nb x 6,856,704) | canvas bf16 (nb x 27,426,816)
    const size_t X1B   = (size_t)HWp*64*2;          // 6,856,704
    const size_t CANB  = (size_t)NYg*NXg*64*2;      // 27,426,816
    const size_t MASKB = (size_t)MASKW*4;           // 32,768
    const size_t BASE  = 256 + 73728 + 147456 + 8192 + 8192;   // 237,824
    const size_t NEED1 = BASE + MASKB + X1B + CANB;
    const size_t NEED4 = BASE + 4*(MASKB + X1B + CANB);
    if (ws_size < NEED1) {
        sentinel_kernel<<<1, 64, 0, stream>>>(out, 10000.0f + (float)(ws_size >> 20));
        return;
    }
    const int nb = (ws_size >= NEED4) ? 4 : 1;
    char* ws = (char*)d_ws;
    int* flags = (int*)ws;
    unsigned short* wt1 = (unsigned short*)(ws + 256);
    unsigned short* wt2 = (unsigned short*)(ws + 256 + 73728);
    unsigned short* whh = (unsigned short*)(ws + 256 + 73728 + 147456);
    unsigned short* whl = (unsigned short*)(ws + 256 + 73728 + 147456 + 8192);
    unsigned int*   maskbuf = (unsigned int*)(ws + BASE);
    unsigned short* x1  = (unsigned short*)(ws + BASE + (size_t)nb*MASKB);
    unsigned short* canvas = (unsigned short*)(ws + BASE + (size_t)nb*(MASKB + X1B));

    detect_all<<<1, 1024, 0, stream>>>(
        din[0], din[3], din[4], din[5], din[6], din[7],
        din[8], din[9], din[10], din[11], din[12],
        din[13], din[14], din[15], din[16], din[17],
        din[18], din[19], din[20], din[21], din[22], din[23], flags);
    prep_weights<<<288, 256, 0, stream>>>(
        din[8], din[13], din[18], din[20], din[22], wt1, wt2, whh, whl, flags);

    if (nb == 4) {
        hipMemsetAsync(maskbuf, 0, 4*MASKB, stream);
        pfn_scatter<<<dim3(NPIL/4, 4), 256, 0, stream>>>(
            din[0], coords, din[3], din[4], din[5], din[6], din[7], flags, 0, maskbuf, canvas);
        conv1_mfma<<<dim3(14, 31, 4), 256, 0, stream>>>(
            canvas, maskbuf, wt1, din[9], din[10], din[11], din[12], flags, x1);
        conv2_mfma<<<dim3(14, 31, 4), 256, 0, stream>>>(
            x1, wt2, whh, whl, din[14], din[15], din[16], din[17],
            din[19], din[21], din[23], flags, 0, out);
    } else {
        for (int b = 0; b < BATCH; ++b) {
            hipMemsetAsync(maskbuf, 0, MASKB, stream);
            pfn_scatter<<<dim3(NPIL/4, 1), 256, 0, stream>>>(
                din[0], coords, din[3], din[4], din[5], din[6], din[7], flags, b, maskbuf, canvas);
            conv1_mfma<<<dim3(14, 31, 1), 256, 0, stream>>>(
                canvas, maskbuf, wt1, din[9], din[10], din[11], din[12], flags, x1);
            conv2_mfma<<<dim3(14, 31, 1), 256, 0, stream>>>(
                x1, wt2, whh, whl, din[14], din[15], din[16], din[17],
                din[19], din[21], din[23], flags, b, out);
        }
    }
}

// Round 7
// 392.444 us; speedup vs baseline: 1.0559x; 1.0559x over previous
//
#include <hip/hip_runtime.h>

// ---------------- constants ----------------
#define BATCH 4
#define NPIL 12000
#define NPTS 32
#define NCH 9
#define NXg 432
#define NYg 496
#define OHh 248
#define OWw 216
#define HWp (OHh*OWw)          // 53568
#define CAN_STRIDE ((size_t)NYg*NXg*64)      // ushort elems (bf16 canvas)
#define X1_STRIDE  ((size_t)OHh*OWw*64)      // ushort elems (bf16 x1)
#define MASKW 8192                            // mask words per batch (padded)

typedef __bf16 bf16x8 __attribute__((ext_vector_type(8)));
typedef float  f32x4  __attribute__((ext_vector_type(4)));

__device__ __forceinline__ bf16x8 as_bf16x8(uint4 u) {
    union { uint4 u; bf16x8 b; } c; c.u = u; return c.b;
}

__device__ __forceinline__ float b2f(unsigned int u) {
    union { unsigned int i; float f; } x; x.i = (u & 0xffffu) << 16; return x.f;
}
__device__ __forceinline__ unsigned short f2b(float f) {
    union { float f; unsigned int i; } x; x.f = f;
    unsigned int r = x.i + 0x7fffu + ((x.i >> 16) & 1u);   // RNE
    return (unsigned short)(r >> 16);
}
__device__ __forceinline__ float ldin(const void* p, int i, int isbf) {
    return isbf ? b2f(((const unsigned short*)p)[i]) : ((const float*)p)[i];
}

__global__ void sentinel_kernel(float* out, float val) {
    if (threadIdx.x == 0) out[0] = val;
}

// ---------------- per-tensor dtype detector (robustness; all fp32 in practice) ----------------
__device__ __forceinline__ int plaus16(unsigned short h) {
    if ((h & 0x7fffu) == 0) return 1;
    unsigned e = (h >> 7) & 0xffu;
    return (e >= 106 && e <= 132) ? 1 : 0;
}

__global__ __launch_bounds__(1024) void detect_all(
    const void* q0,  const void* q1,  const void* q2,  const void* q3,
    const void* q4,  const void* q5,  const void* q6,  const void* q7,
    const void* q8,  const void* q9,  const void* q10, const void* q11,
    const void* q12, const void* q13, const void* q14, const void* q15,
    const void* q16, const void* q17, const void* q18, const void* q19,
    const void* q20, const void* q21, int* __restrict__ flags)
{
    __shared__ int votes[22];
    const void* ptrs[22] = {q0,q1,q2,q3,q4,q5,q6,q7,q8,q9,q10,q11,
                            q12,q13,q14,q15,q16,q17,q18,q19,q20,q21};
    const int Ks[22]   = {64,64,32,32,32,32,64,32,32,32,32,64,64,64,64,64,64,3,64,7,64,2};
    const int didx[22] = {0,3,4,5,6,7,8,9,10,11,12,13,14,15,16,17,18,19,20,21,22,23};
    const int tid = threadIdx.x;
    if (tid < 22) votes[tid] = 0;
    __syncthreads();
    int off = 0;
    #pragma unroll 1
    for (int t = 0; t < 22; ++t) {
        const int K = Ks[t];
        if (tid >= off && tid < off + K) {
            unsigned w = ((const unsigned*)ptrs[t])[tid - off];
            if (plaus16((unsigned short)w) && plaus16((unsigned short)(w >> 16)))
                atomicAdd(&votes[t], 1);
        }
        off += K;
    }
    __syncthreads();
    if (tid < 22) {
        int isbf;
        if (tid == 17 || tid == 19 || tid == 21) {
            int pv = votes[17] + votes[19] + votes[21];
            isbf = (pv * 4 >= 3 * 12);
        } else {
            isbf = (votes[tid] * 4 >= 3 * Ks[tid]);
        }
        flags[didx[tid]] = isbf;
    }
}

// ---------------- weight prep (+ mask zeroing, replaces a memset launch) ----------------
__global__ __launch_bounds__(256) void prep_weights(
    const void* __restrict__ w1, const void* __restrict__ w2,
    const void* __restrict__ cls_w, const void* __restrict__ reg_w, const void* __restrict__ dir_w,
    unsigned short* __restrict__ wt1, unsigned short* __restrict__ wt2,
    unsigned short* __restrict__ whh, unsigned short* __restrict__ whl,
    unsigned int* __restrict__ mask, int mask_words,
    const int* __restrict__ flags)
{
    const int f1 = flags[8], f2 = flags[13];
    int i = blockIdx.x * 256 + threadIdx.x;
    if (i < mask_words) mask[i] = 0u;
    if (i < 64*64*9) {
        int kx = i % 3; int t = i / 3; int ky = t % 3; t /= 3; int ic = t % 64; int oc = t / 64;
        wt1[((size_t)(ky*3 + kx)*64 + oc)*64 + ic] = f2b(ldin(w1, i, f1));
    }
    if (i < 128*64*9) {
        int kx = i % 3; int t = i / 3; int ky = t % 3; t /= 3; int ic = t % 64; int oc = t / 64;
        wt2[((size_t)(ky*3 + kx)*128 + oc)*64 + ic] = f2b(ldin(w2, i, f2));
    }
    if (i < 32*128) {
        int ic = i & 127, o = i >> 7;
        float wv = 0.f;
        if (o < 6)       wv = ldin(cls_w, o*128 + ic, flags[18]);
        else if (o < 20) wv = ldin(reg_w, (o-6)*128 + ic, flags[20]);
        else if (o < 24) wv = ldin(dir_w, (o-20)*128 + ic, flags[22]);
        unsigned short hi = f2b(wv);
        whh[i] = hi;
        whl[i] = f2b(wv - b2f(hi));
    }
}

// ---------------- PFN + scatter, canvas NHWC bf16 [NY,NX,64] + occupancy mask ----------------
__global__ __launch_bounds__(256) void pfn_scatter(
    const void* __restrict__ pillars, const int* __restrict__ coords,
    const void* __restrict__ pfn_w,
    const void* __restrict__ g, const void* __restrict__ bb,
    const void* __restrict__ m, const void* __restrict__ v,
    const int* __restrict__ flags, int b0,
    unsigned int* __restrict__ mask,
    unsigned short* __restrict__ canvas)
{
    __shared__ float lds[4][NPTS*NCH];
    const int wslot = threadIdx.x >> 6;
    const int lane  = threadIdx.x & 63;
    const int p = blockIdx.x * 4 + wslot;
    const int b = b0 + blockIdx.y;
    canvas += (size_t)blockIdx.y * CAN_STRIDE;
    mask   += (size_t)blockIdx.y * MASKW;
    const size_t pg = (size_t)b * NPIL + p;

    if (flags[0]) {
        const unsigned short* src = (const unsigned short*)pillars + pg * (NPTS*NCH);
        for (int idx = lane; idx < NPTS*NCH; idx += 64) lds[wslot][idx] = b2f(src[idx]);
    } else {
        const float4* src = (const float4*)((const float*)pillars + pg * (NPTS*NCH));
        for (int idx = lane; idx < (NPTS*NCH)/4; idx += 64)
            *(float4*)&lds[wslot][idx*4] = src[idx];
    }
    float w[NCH];
    const int fW = flags[3];
    #pragma unroll
    for (int c = 0; c < NCH; ++c) w[c] = ldin(pfn_w, lane*NCH + c, fW);
    float s = ldin(g, lane, flags[4]) / sqrtf(ldin(v, lane, flags[7]) + 1e-5f);
    float t = ldin(bb, lane, flags[5]) - ldin(m, lane, flags[6]) * s;
    __syncthreads();

    float mx = 0.0f;
    #pragma unroll 4
    for (int n = 0; n < NPTS; ++n) {
        const float* r = &lds[wslot][n*NCH];
        float acc = r[0] * w[0];
        #pragma unroll
        for (int c = 1; c < NCH; ++c) acc = fmaf(r[c], w[c], acc);
        mx = fmaxf(mx, fmaxf(fmaf(acc, s, t), 0.0f));
    }
    const int cx = coords[pg*2], cy = coords[pg*2 + 1];
    if (cx + cy != 0 && cx >= 0 && cx < NXg && cy >= 0 && cy < NYg) {
        const int cell = cy*NXg + cx;
        canvas[(size_t)cell*64 + lane] = f2b(mx);
        if (lane == 0) atomicOr(&mask[cell >> 5], 1u << (cell & 31));
    }
}

// B-fragment loader for conv1 (direct from L2-resident wt1)
#define LDB1(buf, tap, ks) { \
    _Pragma("unroll") \
    for (int j_ = 0; j_ < 4; ++j_) \
        buf[j_] = *(const uint4*)&wt[((size_t)((tap)*64 + j_*16 + lr))*64 + (ks)*32 + lg*8]; \
}

// ---------------- conv1 (MFMA): canvas bf16 -> x1 bf16 [248,216,64], stride 2 ----------------
// r4-verified version: 256 thr, 4 waves x 4 oy m-tiles (16-oy tile). B direct from global wt1
// with 2-phase register prefetch. Mask-gated canvas reads. LDS 67,584 -> 2 blk/CU.
__global__ __launch_bounds__(256, 2) void conv1_mfma(
    const unsigned short* __restrict__ canvas,
    const unsigned int* __restrict__ mask,
    const unsigned short* __restrict__ wt,     // bf16 [9][64 oc][64 ic]
    const void* __restrict__ g, const void* __restrict__ bb,
    const void* __restrict__ m, const void* __restrict__ v,
    const int* __restrict__ flags,
    unsigned short* __restrict__ x1)
{
    __shared__ __align__(16) uint4 lin[16*33*8];   // 67,584 B
    const int tid = threadIdx.x;
    const int w = tid >> 6, l = tid & 63;
    const int lr = l & 15, lg = l >> 4;
    const int px0 = blockIdx.x * 16, oy0 = blockIdx.y * 16;
    canvas += (size_t)blockIdx.z * CAN_STRIDE;
    mask   += (size_t)blockIdx.z * MASKW;
    x1     += (size_t)blockIdx.z * X1_STRIDE;

    f32x4 acc[4][4];
    #pragma unroll
    for (int t = 0; t < 4; ++t)
        #pragma unroll
        for (int n = 0; n < 4; ++n) acc[t][n] = (f32x4){0.f,0.f,0.f,0.f};

    uint4 wbA[4], wbB[4];
    LDB1(wbA, 0, 0);

    #pragma unroll 1
    for (int ky = 0; ky < 3; ++ky) {
        __syncthreads();                       // drain readers of lin
        for (int q = tid; q < 16*33*8; q += 256) {
            int sl = q & 7, t2 = q >> 3, c = t2 % 33, r = t2 / 33;
            int iy = 2*oy0 + ky - 1 + 2*r, gx = 2*px0 - 1 + c;
            uint4 d = make_uint4(0u,0u,0u,0u);
            if ((unsigned)iy < (unsigned)NYg && (unsigned)gx < (unsigned)NXg) {
                const int cell = iy*NXg + gx;
                if ((mask[cell >> 5] >> (cell & 31)) & 1u)
                    d = *(const uint4*)&canvas[(size_t)cell*64 + sl*8];
            }
            lin[(r*33 + c)*8 + (sl ^ ((c >> 1) & 7))] = d;
        }
        __syncthreads();
        #pragma unroll 1
        for (int kx = 0; kx < 3; ++kx) {
            const int tap = ky*3 + kx;
            const int c = 2*lr + kx;
            const int key = (c >> 1) & 7;
            // phase 0: ks=0 with wbA; prefetch ks=1 -> wbB
            LDB1(wbB, tap, 1);
            #pragma unroll
            for (int t = 0; t < 4; ++t) {
                const int base = ((4*w + t)*33 + c)*8;
                bf16x8 a0 = as_bf16x8(lin[base + (lg ^ key)]);
                #pragma unroll
                for (int n = 0; n < 4; ++n)
                    acc[t][n] = __builtin_amdgcn_mfma_f32_16x16x32_bf16(a0, as_bf16x8(wbA[n]), acc[t][n], 0, 0, 0);
            }
            // phase 1: ks=1 with wbB; prefetch next tap ks=0 -> wbA
            if (tap < 8) LDB1(wbA, tap + 1, 0);
            #pragma unroll
            for (int t = 0; t < 4; ++t) {
                const int base = ((4*w + t)*33 + c)*8;
                bf16x8 a1 = as_bf16x8(lin[base + ((4 + lg) ^ key)]);
                #pragma unroll
                for (int n = 0; n < 4; ++n)
                    acc[t][n] = __builtin_amdgcn_mfma_f32_16x16x32_bf16(a1, as_bf16x8(wbB[n]), acc[t][n], 0, 0, 0);
            }
        }
    }
    float s[4], tt[4];
    #pragma unroll
    for (int n = 0; n < 4; ++n) {
        const int oc = n*16 + lr;
        s[n]  = ldin(g, oc, flags[9]) / sqrtf(ldin(v, oc, flags[12]) + 1e-5f);
        tt[n] = ldin(bb, oc, flags[10]) - ldin(m, oc, flags[11]) * s[n];
    }
    // D: col = lr = oc, row = lg*4+r = px
    #pragma unroll
    for (int t = 0; t < 4; ++t) {
        const int oy = oy0 + 4*w + t;
        if (oy >= OHh) continue;
        #pragma unroll
        for (int r = 0; r < 4; ++r) {
            const int px = px0 + lg*4 + r;
            if (px >= OWw) continue;
            unsigned short* orow = &x1[((size_t)oy*OWw + px)*64 + lr];
            #pragma unroll
            for (int n = 0; n < 4; ++n)
                orow[n*16] = f2b(fmaxf(fmaf(acc[t][n][r], s[n], tt[n]), 0.f));
        }
    }
}

// ---------------- conv2 (MFMA) + fused heads ----------------
// r2-verified main loop: 256 thr, 4 waves x 4 oy m-tiles x 8 n-tiles, 16-oy tile.
// lin staged once; lw double-buffered with register prefetch (1 barrier/tap). LDS 74,240
// -> 2 blk/CU. Epilogue: r2's hi/lo 3-pass, but head weights loaded PER-USE from L2
// (r5/r6-verified pattern) instead of 128 pre-held regs -> removes r2's ~37MB spill.
__global__ __launch_bounds__(256, 2) void conv2_mfma(
    const unsigned short* __restrict__ x1,
    const unsigned short* __restrict__ wt,     // bf16 [9][128 oc][64 ic]
    const unsigned short* __restrict__ whh,    // bf16 [32 o][128 ic] head W hi
    const unsigned short* __restrict__ whl,    // bf16 [32 o][128 ic] head W lo
    const void* __restrict__ g, const void* __restrict__ bb,
    const void* __restrict__ m, const void* __restrict__ v,
    const void* __restrict__ cls_b, const void* __restrict__ reg_b, const void* __restrict__ dir_b,
    const int* __restrict__ flags, int b0,
    float* __restrict__ out)
{
    __shared__ __align__(16) char smem[74240];     // lin 41,472 | lw 32,768 ; P overlays 65,536
    uint4* lin = (uint4*)smem;
    uint4 (*lw)[128*8] = (uint4 (*)[128*8])(smem + 41472);
    unsigned short* P = (unsigned short*)smem;

    const int tid = threadIdx.x;
    const int w = tid >> 6, l = tid & 63;
    const int lr = l & 15, lg = l >> 4;
    const int px0 = blockIdx.x * 16, oy0 = blockIdx.y * 16;
    const int b = b0 + blockIdx.z;
    x1 += (size_t)blockIdx.z * X1_STRIDE;

    for (int q = tid; q < 18*18*8; q += 256) {
        int sl = q & 7, t2 = q >> 3, c = t2 % 18, r = t2 / 18;
        int iy = oy0 - 1 + r, gx = px0 - 1 + c;
        uint4 d = make_uint4(0u,0u,0u,0u);
        if ((unsigned)iy < (unsigned)OHh && (unsigned)gx < (unsigned)OWw)
            d = *(const uint4*)&x1[((size_t)(iy*OWw + gx))*64 + sl*8];
        lin[(r*18 + c)*8 + (sl ^ (c & 7))] = d;
    }
    uint4 wreg[4];
    #pragma unroll
    for (int i = 0; i < 4; ++i) {
        const int q = tid + i*256;
        wreg[i] = *(const uint4*)&wt[((size_t)(q >> 3))*64 + (q & 7)*8];
    }
    #pragma unroll
    for (int i = 0; i < 4; ++i) {
        const int q = tid + i*256, sl = q & 7, oc = q >> 3;
        lw[0][oc*8 + (sl ^ (oc & 7))] = wreg[i];
    }
    __syncthreads();

    f32x4 acc[4][8];
    #pragma unroll
    for (int t = 0; t < 4; ++t)
        #pragma unroll
        for (int n = 0; n < 8; ++n) acc[t][n] = (f32x4){0.f,0.f,0.f,0.f};

    #pragma unroll 1
    for (int tap = 0; tap < 9; ++tap) {
        const int ky = tap / 3, kx = tap - 3*ky;
        const int cur = tap & 1;
        if (tap < 8) {                          // prefetch next tap's weights to regs
            #pragma unroll
            for (int i = 0; i < 4; ++i) {
                const int q = tid + i*256;
                wreg[i] = *(const uint4*)&wt[((size_t)(tap+1)*128 + (q >> 3))*64 + (q & 7)*8];
            }
        }
        const int c = lr + kx;
        const int key = c & 7;
        bf16x8 af[4][2];
        #pragma unroll
        for (int t = 0; t < 4; ++t) {
            const int base = ((4*w + t + ky)*18 + c)*8;
            af[t][0] = as_bf16x8(lin[base + (lg ^ key)]);
            af[t][1] = as_bf16x8(lin[base + ((4 + lg) ^ key)]);
        }
        #pragma unroll
        for (int n = 0; n < 8; ++n) {
            const int oc = n*16 + lr;
            const bf16x8 b0 = as_bf16x8(lw[cur][oc*8 + (lg ^ (oc & 7))]);
            const bf16x8 b1 = as_bf16x8(lw[cur][oc*8 + ((4 + lg) ^ (oc & 7))]);
            #pragma unroll
            for (int t = 0; t < 4; ++t) {
                acc[t][n] = __builtin_amdgcn_mfma_f32_16x16x32_bf16(af[t][0], b0, acc[t][n], 0, 0, 0);
                acc[t][n] = __builtin_amdgcn_mfma_f32_16x16x32_bf16(af[t][1], b1, acc[t][n], 0, 0, 0);
            }
        }
        if (tap < 8) {
            #pragma unroll
            for (int i = 0; i < 4; ++i) {
                const int q = tid + i*256, sl = q & 7, oc = q >> 3;
                lw[cur ^ 1][oc*8 + (sl ^ (oc & 7))] = wreg[i];
            }
        }
        __syncthreads();
    }

    float s[8], tt[8];
    #pragma unroll
    for (int n = 0; n < 8; ++n) {
        const int oc = n*16 + lr;
        s[n]  = ldin(g, oc, flags[14]) / sqrtf(ldin(v, oc, flags[17]) + 1e-5f);
        tt[n] = ldin(bb, oc, flags[15]) - ldin(m, oc, flags[16]) * s[n];
    }

    // ---- fused heads ----
    float bias0, bias1;
    {
        int o = lr;
        bias0 = (o < 6) ? ldin(cls_b, o, flags[19]) : ldin(reg_b, o - 6, flags[21]);
        o = 16 + lr;
        bias1 = (o < 20) ? ldin(reg_b, o - 6, flags[21])
              : (o < 24) ? ldin(dir_b, o - 20, flags[23]) : 0.f;
    }

    __syncthreads();            // all waves done reading lin/lw before P overlay
    // fill P with hi; convert acc -> lo residual in place
    #pragma unroll
    for (int t = 0; t < 4; ++t) {
        const int pb = ((4*w + t)*16 + lg*4) * 128;
        #pragma unroll
        for (int n = 0; n < 8; ++n) {
            const int kk = 2*n + (lr >> 3), wi = lr & 7;
            #pragma unroll
            for (int r = 0; r < 4; ++r) {
                float val = fmaxf(fmaf(acc[t][n][r], s[n], tt[n]), 0.f);
                unsigned short h = f2b(val);
                P[pb + r*128 + ((kk ^ (lg*4 + r)) << 3) + wi] = h;
                acc[t][n][r] = val - b2f(h);
            }
        }
    }
    __syncthreads();

    f32x4 hacc[4][2];
    #pragma unroll
    for (int t = 0; t < 4; ++t) {
        hacc[t][0] = (f32x4){bias0, bias0, bias0, bias0};
        hacc[t][1] = (f32x4){bias1, bias1, bias1, bias1};
    }
    // pass 1: hi*Whi + hi*Wlo (head weights per-use from L2 -> low reg pressure)
    #pragma unroll
    for (int t = 0; t < 4; ++t) {
        const int mt = 4*w + t;
        bf16x8 pa[4];
        #pragma unroll
        for (int ks = 0; ks < 4; ++ks)
            pa[ks] = as_bf16x8(((const uint4*)P)[(mt*16 + lr)*16 + ((ks*4 + lg) ^ lr)]);
        #pragma unroll
        for (int n = 0; n < 2; ++n)
            #pragma unroll
            for (int ks = 0; ks < 4; ++ks) {
                const int ei = (n*16 + lr)*128 + ks*32 + lg*8;
                hacc[t][n] = __builtin_amdgcn_mfma_f32_16x16x32_bf16(pa[ks], as_bf16x8(*(const uint4*)&whh[ei]), hacc[t][n], 0, 0, 0);
                hacc[t][n] = __builtin_amdgcn_mfma_f32_16x16x32_bf16(pa[ks], as_bf16x8(*(const uint4*)&whl[ei]), hacc[t][n], 0, 0, 0);
            }
    }
    __syncthreads();
    // fill P with lo
    #pragma unroll
    for (int t = 0; t < 4; ++t) {
        const int pb = ((4*w + t)*16 + lg*4) * 128;
        #pragma unroll
        for (int n = 0; n < 8; ++n) {
            const int kk = 2*n + (lr >> 3), wi = lr & 7;
            #pragma unroll
            for (int r = 0; r < 4; ++r)
                P[pb + r*128 + ((kk ^ (lg*4 + r)) << 3) + wi] = f2b(acc[t][n][r]);
        }
    }
    __syncthreads();
    // pass 2: lo*Whi
    #pragma unroll
    for (int t = 0; t < 4; ++t) {
        const int mt = 4*w + t;
        bf16x8 pa[4];
        #pragma unroll
        for (int ks = 0; ks < 4; ++ks)
            pa[ks] = as_bf16x8(((const uint4*)P)[(mt*16 + lr)*16 + ((ks*4 + lg) ^ lr)]);
        #pragma unroll
        for (int n = 0; n < 2; ++n)
            #pragma unroll
            for (int ks = 0; ks < 4; ++ks) {
                const int ei = (n*16 + lr)*128 + ks*32 + lg*8;
                hacc[t][n] = __builtin_amdgcn_mfma_f32_16x16x32_bf16(pa[ks], as_bf16x8(*(const uint4*)&whh[ei]), hacc[t][n], 0, 0, 0);
            }
    }

    const size_t regbase = (size_t)BATCH*6*HWp;
    const size_t dirbase = regbase + (size_t)BATCH*14*HWp;
    const int pxw = px0 + lg*4;
    #pragma unroll
    for (int n = 0; n < 2; ++n) {
        const int o = n*16 + lr;
        float* plane;
        bool valid = (pxw < OWw);
        if (o < 6)       plane = out + ((size_t)b*6 + o)*HWp;
        else if (o < 20) plane = out + regbase + ((size_t)b*14 + (o - 6))*HWp;
        else if (o < 24) plane = out + dirbase + ((size_t)b*4 + (o - 20))*HWp;
        else valid = false;
        if (!valid) continue;
        #pragma unroll
        for (int t = 0; t < 4; ++t) {
            const int oy = oy0 + 4*w + t;
            if (oy < OHh)
                *(float4*)&plane[(size_t)oy*OWw + pxw] = *(float4*)&hacc[t][n];
        }
    }
}

extern "C" void kernel_launch(void* const* d_in, const int* in_sizes, int n_in,
                              void* d_out, int out_size, void* d_ws, size_t ws_size,
                              hipStream_t stream) {
    static const int EXPECT[24] = {13824000,96000,48000,576,64,64,64,64,36864,
                                   64,64,64,64,73728,128,128,128,128,768,6,1792,14,512,4};
    const void* din[24];
    {
        bool used[24] = {false};
        int perm[24];
        bool ok = (n_in >= 24);
        if (ok) {
            for (int j = 0; j < 24 && ok; ++j) {
                perm[j] = -1;
                for (int i = 0; i < 24; ++i)
                    if (!used[i] && in_sizes[i] == EXPECT[j]) { perm[j] = i; used[i] = true; break; }
                if (perm[j] < 0) ok = false;
            }
        }
        for (int j = 0; j < 24; ++j) din[j] = d_in[ok ? perm[j] : j];
        if (!ok) {
            sentinel_kernel<<<1, 64, 0, stream>>>((float*)d_out, 13000.0f + n_in);
            return;
        }
    }
    const int* coords = (const int*)din[1];
    float* out = (float*)d_out;

    // layout: flags 256 | wt1 73,728 | wt2 147,456 | whh 8,192 | whl 8,192 |
    //         mask (nb x 32,768) | x1 bf16 (nb x 6,856,704) | canvas bf16 (nb x 27,426,816)
    const size_t X1B   = (size_t)HWp*64*2;          // 6,856,704
    const size_t CANB  = (size_t)NYg*NXg*64*2;      // 27,426,816
    const size_t MASKB = (size_t)MASKW*4;           // 32,768
    const size_t BASE  = 256 + 73728 + 147456 + 8192 + 8192;   // 237,824
    const size_t NEED1 = BASE + MASKB + X1B + CANB;
    const size_t NEED4 = BASE + 4*(MASKB + X1B + CANB);
    if (ws_size < NEED1) {
        sentinel_kernel<<<1, 64, 0, stream>>>(out, 10000.0f + (float)(ws_size >> 20));
        return;
    }
    const int nb = (ws_size >= NEED4) ? 4 : 1;
    char* ws = (char*)d_ws;
    int* flags = (int*)ws;
    unsigned short* wt1 = (unsigned short*)(ws + 256);
    unsigned short* wt2 = (unsigned short*)(ws + 256 + 73728);
    unsigned short* whh = (unsigned short*)(ws + 256 + 73728 + 147456);
    unsigned short* whl = (unsigned short*)(ws + 256 + 73728 + 147456 + 8192);
    unsigned int*   maskbuf = (unsigned int*)(ws + BASE);
    unsigned short* x1  = (unsigned short*)(ws + BASE + (size_t)nb*MASKB);
    unsigned short* canvas = (unsigned short*)(ws + BASE + (size_t)nb*(MASKB + X1B));

    detect_all<<<1, 1024, 0, stream>>>(
        din[0], din[3], din[4], din[5], din[6], din[7],
        din[8], din[9], din[10], din[11], din[12],
        din[13], din[14], din[15], din[16], din[17],
        din[18], din[19], din[20], din[21], din[22], din[23], flags);
    prep_weights<<<288, 256, 0, stream>>>(
        din[8], din[13], din[18], din[20], din[22], wt1, wt2, whh, whl,
        maskbuf, nb*MASKW, flags);

    if (nb == 4) {
        pfn_scatter<<<dim3(NPIL/4, 4), 256, 0, stream>>>(
            din[0], coords, din[3], din[4], din[5], din[6], din[7], flags, 0, maskbuf, canvas);
        conv1_mfma<<<dim3(14, 16, 4), 256, 0, stream>>>(
            canvas, maskbuf, wt1, din[9], din[10], din[11], din[12], flags, x1);
        conv2_mfma<<<dim3(14, 16, 4), 256, 0, stream>>>(
            x1, wt2, whh, whl, din[14], din[15], din[16], din[17],
            din[19], din[21], din[23], flags, 0, out);
    } else {
        for (int b = 0; b < BATCH; ++b) {
            if (b) hipMemsetAsync(maskbuf, 0, MASKB, stream);   // b=0 zeroed by prep_weights
            pfn_scatter<<<dim3(NPIL/4, 1), 256, 0, stream>>>(
                din[0], coords, din[3], din[4], din[5], din[6], din[7], flags, b, maskbuf, canvas);
            conv1_mfma<<<dim3(14, 16, 1), 256, 0, stream>>>(
                canvas, maskbuf, wt1, din[9], din[10], din[11], din[12], flags, x1);
            conv2_mfma<<<dim3(14, 16, 1), 256, 0, stream>>>(
                x1, wt2, whh, whl, din[14], din[15], din[16], din[17],
                din[19], din[21], din[23], flags, b, out);
        }
    }
}

// Round 8
// 339.758 us; speedup vs baseline: 1.2197x; 1.1551x over previous
//
#include <hip/hip_runtime.h>

// ---------------- constants ----------------
#define BATCH 4
#define NPIL 12000
#define NPTS 32
#define NCH 9
#define NXg 432
#define NYg 496
#define OHh 248
#define OWw 216
#define HWp (OHh*OWw)          // 53568
#define CAN_STRIDE ((size_t)NYg*NXg*64)      // ushort elems (bf16 canvas)
#define X1_STRIDE  ((size_t)OHh*OWw*64)      // ushort elems (bf16 x1)
#define MASKW 8192                            // mask words per batch (padded)

typedef __bf16 bf16x8 __attribute__((ext_vector_type(8)));
typedef float  f32x4  __attribute__((ext_vector_type(4)));

__device__ __forceinline__ bf16x8 as_bf16x8(uint4 u) {
    union { uint4 u; bf16x8 b; } c; c.u = u; return c.b;
}

__device__ __forceinline__ float b2f(unsigned int u) {
    union { unsigned int i; float f; } x; x.i = (u & 0xffffu) << 16; return x.f;
}
__device__ __forceinline__ unsigned short f2b(float f) {
    union { float f; unsigned int i; } x; x.f = f;
    unsigned int r = x.i + 0x7fffu + ((x.i >> 16) & 1u);   // RNE
    return (unsigned short)(r >> 16);
}
__device__ __forceinline__ float ldin(const void* p, int i, int isbf) {
    return isbf ? b2f(((const unsigned short*)p)[i]) : ((const float*)p)[i];
}

// async global->LDS DMA, 16B per lane. LDS dest must be (wave-uniform base + lane*16);
// global source may be fully per-lane (m173 pattern: swizzle lives on the SOURCE address).
__device__ __forceinline__ void async_load16(const void* gsrc, void* ldst) {
    __builtin_amdgcn_global_load_lds(
        (const __attribute__((address_space(1))) unsigned char*)gsrc,
        (__attribute__((address_space(3))) unsigned char*)ldst, 16, 0, 0);
}

__global__ void sentinel_kernel(float* out, float val) {
    if (threadIdx.x == 0) out[0] = val;
}

// ---------------- per-tensor dtype detector (robustness; all fp32 in practice) ----------------
__device__ __forceinline__ int plaus16(unsigned short h) {
    if ((h & 0x7fffu) == 0) return 1;
    unsigned e = (h >> 7) & 0xffu;
    return (e >= 106 && e <= 132) ? 1 : 0;
}

__global__ __launch_bounds__(1024) void detect_all(
    const void* q0,  const void* q1,  const void* q2,  const void* q3,
    const void* q4,  const void* q5,  const void* q6,  const void* q7,
    const void* q8,  const void* q9,  const void* q10, const void* q11,
    const void* q12, const void* q13, const void* q14, const void* q15,
    const void* q16, const void* q17, const void* q18, const void* q19,
    const void* q20, const void* q21, int* __restrict__ flags)
{
    __shared__ int votes[22];
    const void* ptrs[22] = {q0,q1,q2,q3,q4,q5,q6,q7,q8,q9,q10,q11,
                            q12,q13,q14,q15,q16,q17,q18,q19,q20,q21};
    const int Ks[22]   = {64,64,32,32,32,32,64,32,32,32,32,64,64,64,64,64,64,3,64,7,64,2};
    const int didx[22] = {0,3,4,5,6,7,8,9,10,11,12,13,14,15,16,17,18,19,20,21,22,23};
    const int tid = threadIdx.x;
    if (tid < 22) votes[tid] = 0;
    __syncthreads();
    int off = 0;
    #pragma unroll 1
    for (int t = 0; t < 22; ++t) {
        const int K = Ks[t];
        if (tid >= off && tid < off + K) {
            unsigned w = ((const unsigned*)ptrs[t])[tid - off];
            if (plaus16((unsigned short)w) && plaus16((unsigned short)(w >> 16)))
                atomicAdd(&votes[t], 1);
        }
        off += K;
    }
    __syncthreads();
    if (tid < 22) {
        int isbf;
        if (tid == 17 || tid == 19 || tid == 21) {
            int pv = votes[17] + votes[19] + votes[21];
            isbf = (pv * 4 >= 3 * 12);
        } else {
            isbf = (votes[tid] * 4 >= 3 * Ks[tid]);
        }
        flags[didx[tid]] = isbf;
    }
}

// ---------------- weight prep (+ mask & zero-stub clearing) ----------------
__global__ __launch_bounds__(256) void prep_weights(
    const void* __restrict__ w1, const void* __restrict__ w2,
    const void* __restrict__ cls_w, const void* __restrict__ reg_w, const void* __restrict__ dir_w,
    unsigned short* __restrict__ wt1, unsigned short* __restrict__ wt2,
    unsigned short* __restrict__ whh, unsigned short* __restrict__ whl,
    unsigned int* __restrict__ mask, int mask_words,
    unsigned int* __restrict__ zbuf,
    const int* __restrict__ flags)
{
    const int f1 = flags[8], f2 = flags[13];
    int i = blockIdx.x * 256 + threadIdx.x;
    if (i < mask_words) mask[i] = 0u;
    if (i < 16) zbuf[i] = 0u;
    if (i < 64*64*9) {
        int kx = i % 3; int t = i / 3; int ky = t % 3; t /= 3; int ic = t % 64; int oc = t / 64;
        wt1[((size_t)(ky*3 + kx)*64 + oc)*64 + ic] = f2b(ldin(w1, i, f1));
    }
    if (i < 128*64*9) {
        int kx = i % 3; int t = i / 3; int ky = t % 3; t /= 3; int ic = t % 64; int oc = t / 64;
        wt2[((size_t)(ky*3 + kx)*128 + oc)*64 + ic] = f2b(ldin(w2, i, f2));
    }
    if (i < 32*128) {
        int ic = i & 127, o = i >> 7;
        float wv = 0.f;
        if (o < 6)       wv = ldin(cls_w, o*128 + ic, flags[18]);
        else if (o < 20) wv = ldin(reg_w, (o-6)*128 + ic, flags[20]);
        else if (o < 24) wv = ldin(dir_w, (o-20)*128 + ic, flags[22]);
        unsigned short hi = f2b(wv);
        whh[i] = hi;
        whl[i] = f2b(wv - b2f(hi));
    }
}

// ---------------- PFN + scatter, canvas NHWC bf16 [NY,NX,64] + occupancy mask ----------------
__global__ __launch_bounds__(256) void pfn_scatter(
    const void* __restrict__ pillars, const int* __restrict__ coords,
    const void* __restrict__ pfn_w,
    const void* __restrict__ g, const void* __restrict__ bb,
    const void* __restrict__ m, const void* __restrict__ v,
    const int* __restrict__ flags, int b0,
    unsigned int* __restrict__ mask,
    unsigned short* __restrict__ canvas)
{
    __shared__ float lds[4][NPTS*NCH];
    const int wslot = threadIdx.x >> 6;
    const int lane  = threadIdx.x & 63;
    const int p = blockIdx.x * 4 + wslot;
    const int b = b0 + blockIdx.y;
    canvas += (size_t)blockIdx.y * CAN_STRIDE;
    mask   += (size_t)blockIdx.y * MASKW;
    const size_t pg = (size_t)b * NPIL + p;

    if (flags[0]) {
        const unsigned short* src = (const unsigned short*)pillars + pg * (NPTS*NCH);
        for (int idx = lane; idx < NPTS*NCH; idx += 64) lds[wslot][idx] = b2f(src[idx]);
    } else {
        const float4* src = (const float4*)((const float*)pillars + pg * (NPTS*NCH));
        for (int idx = lane; idx < (NPTS*NCH)/4; idx += 64)
            *(float4*)&lds[wslot][idx*4] = src[idx];
    }
    float w[NCH];
    const int fW = flags[3];
    #pragma unroll
    for (int c = 0; c < NCH; ++c) w[c] = ldin(pfn_w, lane*NCH + c, fW);
    float s = ldin(g, lane, flags[4]) / sqrtf(ldin(v, lane, flags[7]) + 1e-5f);
    float t = ldin(bb, lane, flags[5]) - ldin(m, lane, flags[6]) * s;
    __syncthreads();

    float mx = 0.0f;
    #pragma unroll 4
    for (int n = 0; n < NPTS; ++n) {
        const float* r = &lds[wslot][n*NCH];
        float acc = r[0] * w[0];
        #pragma unroll
        for (int c = 1; c < NCH; ++c) acc = fmaf(r[c], w[c], acc);
        mx = fmaxf(mx, fmaxf(fmaf(acc, s, t), 0.0f));
    }
    const int cx = coords[pg*2], cy = coords[pg*2 + 1];
    if (cx + cy != 0 && cx >= 0 && cx < NXg && cy >= 0 && cy < NYg) {
        const int cell = cy*NXg + cx;
        canvas[(size_t)cell*64 + lane] = f2b(mx);
        if (lane == 0) atomicOr(&mask[cell >> 5], 1u << (cell & 31));
    }
}

// B-fragment loader for conv1 (direct from L2-resident wt1)
#define LDB1(buf, tap, ks) { \
    _Pragma("unroll") \
    for (int j_ = 0; j_ < 4; ++j_) \
        buf[j_] = *(const uint4*)&wt[((size_t)((tap)*64 + j_*16 + lr))*64 + (ks)*32 + lg*8]; \
}

// ---------------- conv1 (MFMA): canvas bf16 -> x1 bf16 [248,216,64], stride 2 ----------------
// r4 structure; lin staged via global_load_lds DMA (linear LDS, inverse-swizzled source,
// zero-stub for empty/OOB cells). B direct from wt1 with 2-phase register prefetch.
// LDS 67,584 -> 2 blk/CU.
__global__ __launch_bounds__(256, 2) void conv1_mfma(
    const unsigned short* __restrict__ canvas,
    const unsigned int* __restrict__ mask,
    const unsigned short* __restrict__ wt,     // bf16 [9][64 oc][64 ic]
    const uint4* __restrict__ zbuf,
    const void* __restrict__ g, const void* __restrict__ bb,
    const void* __restrict__ m, const void* __restrict__ v,
    const int* __restrict__ flags,
    unsigned short* __restrict__ x1)
{
    __shared__ __align__(16) uint4 lin[16*33*8];   // 67,584 B
    const int tid = threadIdx.x;
    const int w = tid >> 6, l = tid & 63;
    const int lr = l & 15, lg = l >> 4;
    const int px0 = blockIdx.x * 16, oy0 = blockIdx.y * 16;
    canvas += (size_t)blockIdx.z * CAN_STRIDE;
    mask   += (size_t)blockIdx.z * MASKW;
    x1     += (size_t)blockIdx.z * X1_STRIDE;

    f32x4 acc[4][4];
    #pragma unroll
    for (int t = 0; t < 4; ++t)
        #pragma unroll
        for (int n = 0; n < 4; ++n) acc[t][n] = (f32x4){0.f,0.f,0.f,0.f};

    uint4 wbA[4], wbB[4];
    LDB1(wbA, 0, 0);

    #pragma unroll 1
    for (int ky = 0; ky < 3; ++ky) {
        __syncthreads();                       // drain readers of lin
        for (int q = tid; q < 16*33*8; q += 256) {
            int s = q & 7, t2 = q >> 3, c = t2 % 33, r = t2 / 33;
            int iy = 2*oy0 + ky - 1 + 2*r, gx = 2*px0 - 1 + c;
            const void* src = zbuf;
            if ((unsigned)iy < (unsigned)NYg && (unsigned)gx < (unsigned)NXg) {
                const int cell = iy*NXg + gx;
                if ((mask[cell >> 5] >> (cell & 31)) & 1u)
                    src = &canvas[(size_t)cell*64 + (s ^ ((c >> 1) & 7))*8];
            }
            async_load16(src, &lin[q]);
        }
        __syncthreads();                       // implicit vmcnt(0) drains the DMA
        #pragma unroll 1
        for (int kx = 0; kx < 3; ++kx) {
            const int tap = ky*3 + kx;
            const int c = 2*lr + kx;
            const int key = (c >> 1) & 7;
            // phase 0: ks=0 with wbA; prefetch ks=1 -> wbB
            LDB1(wbB, tap, 1);
            __builtin_amdgcn_s_setprio(1);
            #pragma unroll
            for (int t = 0; t < 4; ++t) {
                const int base = ((4*w + t)*33 + c)*8;
                bf16x8 a0 = as_bf16x8(lin[base + (lg ^ key)]);
                #pragma unroll
                for (int n = 0; n < 4; ++n)
                    acc[t][n] = __builtin_amdgcn_mfma_f32_16x16x32_bf16(a0, as_bf16x8(wbA[n]), acc[t][n], 0, 0, 0);
            }
            __builtin_amdgcn_s_setprio(0);
            // phase 1: ks=1 with wbB; prefetch next tap ks=0 -> wbA
            if (tap < 8) LDB1(wbA, tap + 1, 0);
            __builtin_amdgcn_s_setprio(1);
            #pragma unroll
            for (int t = 0; t < 4; ++t) {
                const int base = ((4*w + t)*33 + c)*8;
                bf16x8 a1 = as_bf16x8(lin[base + ((4 + lg) ^ key)]);
                #pragma unroll
                for (int n = 0; n < 4; ++n)
                    acc[t][n] = __builtin_amdgcn_mfma_f32_16x16x32_bf16(a1, as_bf16x8(wbB[n]), acc[t][n], 0, 0, 0);
            }
            __builtin_amdgcn_s_setprio(0);
        }
    }
    float s[4], tt[4];
    #pragma unroll
    for (int n = 0; n < 4; ++n) {
        const int oc = n*16 + lr;
        s[n]  = ldin(g, oc, flags[9]) / sqrtf(ldin(v, oc, flags[12]) + 1e-5f);
        tt[n] = ldin(bb, oc, flags[10]) - ldin(m, oc, flags[11]) * s[n];
    }
    // D: col = lr = oc, row = lg*4+r = px
    #pragma unroll
    for (int t = 0; t < 4; ++t) {
        const int oy = oy0 + 4*w + t;
        if (oy >= OHh) continue;
        #pragma unroll
        for (int r = 0; r < 4; ++r) {
            const int px = px0 + lg*4 + r;
            if (px >= OWw) continue;
            unsigned short* orow = &x1[((size_t)oy*OWw + px)*64 + lr];
            #pragma unroll
            for (int n = 0; n < 4; ++n)
                orow[n*16] = f2b(fmaxf(fmaf(acc[t][n][r], s[n], tt[n]), 0.f));
        }
    }
}

// ---------------- conv2 (MFMA) + fused heads ----------------
// r2-verified main loop shape (lw double-buffer, 1 barrier/tap) with staging converted to
// global_load_lds DMA (linear LDS dest, inverse-swizzled source). Epilogue = r2-exact
// (pre-held wh/wl; measured 100us — r7's per-use loads hoisted into spill). LDS 74,240
// -> 2 blk/CU.
__global__ __launch_bounds__(256, 2) void conv2_mfma(
    const unsigned short* __restrict__ x1,
    const unsigned short* __restrict__ wt,     // bf16 [9][128 oc][64 ic]
    const unsigned short* __restrict__ whh,    // bf16 [32 o][128 ic] head W hi
    const unsigned short* __restrict__ whl,    // bf16 [32 o][128 ic] head W lo
    const uint4* __restrict__ zbuf,
    const void* __restrict__ g, const void* __restrict__ bb,
    const void* __restrict__ m, const void* __restrict__ v,
    const void* __restrict__ cls_b, const void* __restrict__ reg_b, const void* __restrict__ dir_b,
    const int* __restrict__ flags, int b0,
    float* __restrict__ out)
{
    __shared__ __align__(16) char smem[74240];     // lin 41,472 | lw 32,768 ; P overlays 65,536
    uint4* lin = (uint4*)smem;
    uint4 (*lw)[128*8] = (uint4 (*)[128*8])(smem + 41472);
    unsigned short* P = (unsigned short*)smem;

    const int tid = threadIdx.x;
    const int w = tid >> 6, l = tid & 63;
    const int lr = l & 15, lg = l >> 4;
    const int px0 = blockIdx.x * 16, oy0 = blockIdx.y * 16;
    const int b = b0 + blockIdx.z;
    x1 += (size_t)blockIdx.z * X1_STRIDE;

    // stage lin via DMA (zero-stub for halo OOB)
    for (int q = tid; q < 18*18*8; q += 256) {
        int s = q & 7, t2 = q >> 3, c = t2 % 18, r = t2 / 18;
        int iy = oy0 - 1 + r, gx = px0 - 1 + c;
        const void* src = zbuf;
        if ((unsigned)iy < (unsigned)OHh && (unsigned)gx < (unsigned)OWw)
            src = &x1[((size_t)(iy*OWw + gx))*64 + (s ^ (c & 7))*8];
        async_load16(src, &lin[q]);
    }
    // stage lw[0] (tap 0) via DMA
    #pragma unroll
    for (int i = 0; i < 4; ++i) {
        const int q = tid + i*256, oc = q >> 3, s = q & 7;
        async_load16(&wt[((size_t)oc)*64 + (s ^ (oc & 7))*8], &lw[0][q]);
    }
    __syncthreads();

    f32x4 acc[4][8];
    #pragma unroll
    for (int t = 0; t < 4; ++t)
        #pragma unroll
        for (int n = 0; n < 8; ++n) acc[t][n] = (f32x4){0.f,0.f,0.f,0.f};

    #pragma unroll 1
    for (int tap = 0; tap < 9; ++tap) {
        const int ky = tap / 3, kx = tap - 3*ky;
        const int cur = tap & 1;
        if (tap < 8) {                          // DMA next tap's weights into the other buffer
            #pragma unroll
            for (int i = 0; i < 4; ++i) {
                const int q = tid + i*256, oc = q >> 3, s = q & 7;
                async_load16(&wt[((size_t)((tap+1)*128 + oc))*64 + (s ^ (oc & 7))*8],
                             &lw[cur ^ 1][q]);
            }
        }
        const int c = lr + kx;
        const int key = c & 7;
        bf16x8 af[4][2];
        #pragma unroll
        for (int t = 0; t < 4; ++t) {
            const int base = ((4*w + t + ky)*18 + c)*8;
            af[t][0] = as_bf16x8(lin[base + (lg ^ key)]);
            af[t][1] = as_bf16x8(lin[base + ((4 + lg) ^ key)]);
        }
        __builtin_amdgcn_s_setprio(1);
        #pragma unroll
        for (int n = 0; n < 8; ++n) {
            const int oc = n*16 + lr;
            const bf16x8 b0 = as_bf16x8(lw[cur][oc*8 + (lg ^ (oc & 7))]);
            const bf16x8 b1 = as_bf16x8(lw[cur][oc*8 + ((4 + lg) ^ (oc & 7))]);
            #pragma unroll
            for (int t = 0; t < 4; ++t) {
                acc[t][n] = __builtin_amdgcn_mfma_f32_16x16x32_bf16(af[t][0], b0, acc[t][n], 0, 0, 0);
                acc[t][n] = __builtin_amdgcn_mfma_f32_16x16x32_bf16(af[t][1], b1, acc[t][n], 0, 0, 0);
            }
        }
        __builtin_amdgcn_s_setprio(0);
        __syncthreads();                        // drains DMA; next tap's lw ready
    }

    float s[8], tt[8];
    #pragma unroll
    for (int n = 0; n < 8; ++n) {
        const int oc = n*16 + lr;
        s[n]  = ldin(g, oc, flags[14]) / sqrtf(ldin(v, oc, flags[17]) + 1e-5f);
        tt[n] = ldin(bb, oc, flags[15]) - ldin(m, oc, flags[16]) * s[n];
    }

    // ---- fused heads (r2-exact epilogue: pre-held hi/lo weights) ----
    float bias0, bias1;
    {
        int o = lr;
        bias0 = (o < 6) ? ldin(cls_b, o, flags[19]) : ldin(reg_b, o - 6, flags[21]);
        o = 16 + lr;
        bias1 = (o < 20) ? ldin(reg_b, o - 6, flags[21])
              : (o < 24) ? ldin(dir_b, o - 20, flags[23]) : 0.f;
    }
    uint4 wh[2][4], wl[2][4];
    #pragma unroll
    for (int n = 0; n < 2; ++n)
        #pragma unroll
        for (int ks = 0; ks < 4; ++ks) {
            const int ei = (n*16 + lr)*128 + ks*32 + lg*8;
            wh[n][ks] = *(const uint4*)&whh[ei];
            wl[n][ks] = *(const uint4*)&whl[ei];
        }

    __syncthreads();            // all waves done reading lin/lw before P overlay
    #pragma unroll
    for (int t = 0; t < 4; ++t) {
        const int pb = ((4*w + t)*16 + lg*4) * 128;
        #pragma unroll
        for (int n = 0; n < 8; ++n) {
            const int kk = 2*n + (lr >> 3), wi = lr & 7;
            #pragma unroll
            for (int r = 0; r < 4; ++r) {
                float val = fmaxf(fmaf(acc[t][n][r], s[n], tt[n]), 0.f);
                unsigned short h = f2b(val);
                P[pb + r*128 + ((kk ^ (lg*4 + r)) << 3) + wi] = h;
                acc[t][n][r] = val - b2f(h);
            }
        }
    }
    __syncthreads();

    f32x4 hacc[4][2];
    #pragma unroll
    for (int t = 0; t < 4; ++t) {
        hacc[t][0] = (f32x4){bias0, bias0, bias0, bias0};
        hacc[t][1] = (f32x4){bias1, bias1, bias1, bias1};
    }
    // pass 1: hi*Whi + hi*Wlo
    #pragma unroll
    for (int t = 0; t < 4; ++t) {
        const int mt = 4*w + t;
        bf16x8 pa[4];
        #pragma unroll
        for (int ks = 0; ks < 4; ++ks)
            pa[ks] = as_bf16x8(((const uint4*)P)[(mt*16 + lr)*16 + ((ks*4 + lg) ^ lr)]);
        #pragma unroll
        for (int n = 0; n < 2; ++n)
            #pragma unroll
            for (int ks = 0; ks < 4; ++ks) {
                hacc[t][n] = __builtin_amdgcn_mfma_f32_16x16x32_bf16(pa[ks], as_bf16x8(wh[n][ks]), hacc[t][n], 0, 0, 0);
                hacc[t][n] = __builtin_amdgcn_mfma_f32_16x16x32_bf16(pa[ks], as_bf16x8(wl[n][ks]), hacc[t][n], 0, 0, 0);
            }
    }
    __syncthreads();
    // fill P with lo
    #pragma unroll
    for (int t = 0; t < 4; ++t) {
        const int pb = ((4*w + t)*16 + lg*4) * 128;
        #pragma unroll
        for (int n = 0; n < 8; ++n) {
            const int kk = 2*n + (lr >> 3), wi = lr & 7;
            #pragma unroll
            for (int r = 0; r < 4; ++r)
                P[pb + r*128 + ((kk ^ (lg*4 + r)) << 3) + wi] = f2b(acc[t][n][r]);
        }
    }
    __syncthreads();
    // pass 2: lo*Whi
    #pragma unroll
    for (int t = 0; t < 4; ++t) {
        const int mt = 4*w + t;
        bf16x8 pa[4];
        #pragma unroll
        for (int ks = 0; ks < 4; ++ks)
            pa[ks] = as_bf16x8(((const uint4*)P)[(mt*16 + lr)*16 + ((ks*4 + lg) ^ lr)]);
        #pragma unroll
        for (int n = 0; n < 2; ++n)
            #pragma unroll
            for (int ks = 0; ks < 4; ++ks)
                hacc[t][n] = __builtin_amdgcn_mfma_f32_16x16x32_bf16(pa[ks], as_bf16x8(wh[n][ks]), hacc[t][n], 0, 0, 0);
    }

    const size_t regbase = (size_t)BATCH*6*HWp;
    const size_t dirbase = regbase + (size_t)BATCH*14*HWp;
    const int pxw = px0 + lg*4;
    #pragma unroll
    for (int n = 0; n < 2; ++n) {
        const int o = n*16 + lr;
        float* plane;
        bool valid = (pxw < OWw);
        if (o < 6)       plane = out + ((size_t)b*6 + o)*HWp;
        else if (o < 20) plane = out + regbase + ((size_t)b*14 + (o - 6))*HWp;
        else if (o < 24) plane = out + dirbase + ((size_t)b*4 + (o - 20))*HWp;
        else valid = false;
        if (!valid) continue;
        #pragma unroll
        for (int t = 0; t < 4; ++t) {
            const int oy = oy0 + 4*w + t;
            if (oy < OHh)
                *(float4*)&plane[(size_t)oy*OWw + pxw] = *(float4*)&hacc[t][n];
        }
    }
}

extern "C" void kernel_launch(void* const* d_in, const int* in_sizes, int n_in,
                              void* d_out, int out_size, void* d_ws, size_t ws_size,
                              hipStream_t stream) {
    static const int EXPECT[24] = {13824000,96000,48000,576,64,64,64,64,36864,
                                   64,64,64,64,73728,128,128,128,128,768,6,1792,14,512,4};
    const void* din[24];
    {
        bool used[24] = {false};
        int perm[24];
        bool ok = (n_in >= 24);
        if (ok) {
            for (int j = 0; j < 24 && ok; ++j) {
                perm[j] = -1;
                for (int i = 0; i < 24; ++i)
                    if (!used[i] && in_sizes[i] == EXPECT[j]) { perm[j] = i; used[i] = true; break; }
                if (perm[j] < 0) ok = false;
            }
        }
        for (int j = 0; j < 24; ++j) din[j] = d_in[ok ? perm[j] : j];
        if (!ok) {
            sentinel_kernel<<<1, 64, 0, stream>>>((float*)d_out, 13000.0f + n_in);
            return;
        }
    }
    const int* coords = (const int*)din[1];
    float* out = (float*)d_out;

    // layout: flags 256 | wt1 73,728 | wt2 147,456 | whh 8,192 | whl 8,192 | zbuf 64 |
    //         mask (nb x 32,768) | x1 bf16 (nb x 6,856,704) | canvas bf16 (nb x 27,426,816)
    const size_t X1B   = (size_t)HWp*64*2;          // 6,856,704
    const size_t CANB  = (size_t)NYg*NXg*64*2;      // 27,426,816
    const size_t MASKB = (size_t)MASKW*4;           // 32,768
    const size_t ZOFF  = 256 + 73728 + 147456 + 8192 + 8192;   // 237,824
    const size_t BASE  = ZOFF + 64;                 // 237,888
    const size_t NEED1 = BASE + MASKB + X1B + CANB;
    const size_t NEED4 = BASE + 4*(MASKB + X1B + CANB);
    if (ws_size < NEED1) {
        sentinel_kernel<<<1, 64, 0, stream>>>(out, 10000.0f + (float)(ws_size >> 20));
        return;
    }
    const int nb = (ws_size >= NEED4) ? 4 : 1;
    char* ws = (char*)d_ws;
    int* flags = (int*)ws;
    unsigned short* wt1 = (unsigned short*)(ws + 256);
    unsigned short* wt2 = (unsigned short*)(ws + 256 + 73728);
    unsigned short* whh = (unsigned short*)(ws + 256 + 73728 + 147456);
    unsigned short* whl = (unsigned short*)(ws + 256 + 73728 + 147456 + 8192);
    unsigned int*   zbuf = (unsigned int*)(ws + ZOFF);
    unsigned int*   maskbuf = (unsigned int*)(ws + BASE);
    unsigned short* x1  = (unsigned short*)(ws + BASE + (size_t)nb*MASKB);
    unsigned short* canvas = (unsigned short*)(ws + BASE + (size_t)nb*(MASKB + X1B));

    detect_all<<<1, 1024, 0, stream>>>(
        din[0], din[3], din[4], din[5], din[6], din[7],
        din[8], din[9], din[10], din[11], din[12],
        din[13], din[14], din[15], din[16], din[17],
        din[18], din[19], din[20], din[21], din[22], din[23], flags);
    prep_weights<<<288, 256, 0, stream>>>(
        din[8], din[13], din[18], din[20], din[22], wt1, wt2, whh, whl,
        maskbuf, nb*MASKW, zbuf, flags);

    if (nb == 4) {
        pfn_scatter<<<dim3(NPIL/4, 4), 256, 0, stream>>>(
            din[0], coords, din[3], din[4], din[5], din[6], din[7], flags, 0, maskbuf, canvas);
        conv1_mfma<<<dim3(14, 16, 4), 256, 0, stream>>>(
            canvas, maskbuf, wt1, (const uint4*)zbuf,
            din[9], din[10], din[11], din[12], flags, x1);
        conv2_mfma<<<dim3(14, 16, 4), 256, 0, stream>>>(
            x1, wt2, whh, whl, (const uint4*)zbuf, din[14], din[15], din[16], din[17],
            din[19], din[21], din[23], flags, 0, out);
    } else {
        for (int b = 0; b < BATCH; ++b) {
            if (b) hipMemsetAsync(maskbuf, 0, MASKB, stream);   // b=0 zeroed by prep_weights
            pfn_scatter<<<dim3(NPIL/4, 1), 256, 0, stream>>>(
                din[0], coords, din[3], din[4], din[5], din[6], din[7], flags, b, maskbuf, canvas);
            conv1_mfma<<<dim3(14, 16, 1), 256, 0, stream>>>(
                canvas, maskbuf, wt1, (const uint4*)zbuf,
                din[9], din[10], din[11], din[12], flags, x1);
            conv2_mfma<<<dim3(14, 16, 1), 256, 0, stream>>>(
                x1, wt2, whh, whl, (const uint4*)zbuf, din[14], din[15], din[16], din[17],
                din[19], din[21], din[23], flags, b, out);
        }
    }
}